// Round 6
// baseline (237.490 us; speedup 1.0000x reference)
//
#include <hip/hip_runtime.h>
#include <hip/hip_bf16.h>

#define NN 4096
#define DD 128
#define NS 75
#define TOT (NN * NN)

// k_d2 tiling
#define BT 128
#define KCC 32
#define NBD2 (NN / BT)                      // 32
#define GRID_D2 (NBD2 * (NBD2 + 1) / 2)     // 528

// sweep tiling: 128x128 triangle tiles, each split into two 64-row halves.
#define SB2 128
#define NBSW2 (NN / SB2)                    // 32
#define GRID_SW2 (NBSW2 * (NBSW2 + 1) / 2)  // 528  (x2 halves in grid.y)

typedef float v2f __attribute__((ext_vector_type(2)));

__device__ __forceinline__ float fexp2(float v) { return __builtin_amdgcn_exp2f(v); }

// linear index -> (bi, bj) with bi <= bj, row-major over upper triangle
__device__ __forceinline__ void tri_decode(int t, int nb, int& bi, int& bj) {
    int b = 0, rem = t;
    while (rem >= nb - b) { rem -= nb - b; ++b; }   // uniform across block -> scalar
    bi = b; bj = b + rem;
}

// ---------------- ws layout (bytes) ----------------
// 0                       : double dist_sum
// 8                       : unsigned long long nz_count
// 16                      : double KL[NS]
// 16 + 8*NS               : double KK[NS]
// 16 + 16*NS              : float sq[NN]
// 16 + 16*NS + 4*NN       : float csig[NS]   (log2e / sigma_s^2)
// 16 + 16*NS + 4*NN + 4*NS: float copt

__global__ void k_rowsq(const float* __restrict__ x, float* __restrict__ sq,
                        double* __restrict__ dsum, unsigned long long* __restrict__ nzc) {
    int tid = blockIdx.x * blockDim.x + threadIdx.x;
    if (tid == 0) { *dsum = 0.0; *nzc = 0ull; }
    if (tid < NN) {
        const float4* row = (const float4*)(x + (size_t)tid * DD);
        float s = 0.f;
#pragma unroll
        for (int i = 0; i < DD / 4; ++i) {
            float4 v = row[i];
            s += v.x * v.x + v.y * v.y + v.z * v.z + v.w * v.w;
        }
        sq[tid] = s;
    }
}

// 128x128 output tile per block, upper-triangle grid, mirrored writes.
__launch_bounds__(256)
__global__ void k_d2(const float* __restrict__ x, const float* __restrict__ sq,
                     float* __restrict__ d2, double* __restrict__ dsum,
                     unsigned long long* __restrict__ nzc) {
    __shared__ float at[KCC][BT + 4];   // stride 132: 16B-aligned b128 reads, writes 4-way max
    __shared__ float btl[KCC][BT + 4];
    __shared__ double red_d[4];
    __shared__ int red_n[4];

    int bi, bj;
    tri_decode(blockIdx.x, NBD2, bi, bj);
    const int r0 = bi * BT, c0 = bj * BT;
    const int tid = threadIdx.x;
    const int tx = tid & 31;   // col group: 4 cols
    const int ty = tid >> 5;   // row group: 16 rows

    float acc[16][4];
#pragma unroll
    for (int r = 0; r < 16; ++r)
#pragma unroll
        for (int c = 0; c < 4; ++c) acc[r][c] = 0.f;

    for (int kb = 0; kb < DD; kb += KCC) {
#pragma unroll
        for (int i = 0; i < 4; ++i) {
            int idx = tid + 256 * i;       // 0..1023
            int row = idx >> 3;            // 0..127
            int k4 = (idx & 7) * 4;        // 0..28
            float4 va = *(const float4*)(x + (size_t)(r0 + row) * DD + kb + k4);
            at[k4 + 0][row] = va.x; at[k4 + 1][row] = va.y;
            at[k4 + 2][row] = va.z; at[k4 + 3][row] = va.w;
            float4 vb = *(const float4*)(x + (size_t)(c0 + row) * DD + kb + k4);
            btl[k4 + 0][row] = vb.x; btl[k4 + 1][row] = vb.y;
            btl[k4 + 2][row] = vb.z; btl[k4 + 3][row] = vb.w;
        }
        __syncthreads();
#pragma unroll
        for (int kk = 0; kk < KCC; ++kk) {
            float av[16];
            *(float4*)&av[0]  = *(const float4*)&at[kk][ty * 16 + 0];
            *(float4*)&av[4]  = *(const float4*)&at[kk][ty * 16 + 4];
            *(float4*)&av[8]  = *(const float4*)&at[kk][ty * 16 + 8];
            *(float4*)&av[12] = *(const float4*)&at[kk][ty * 16 + 12];
            float4 b4 = *(const float4*)&btl[kk][tx * 4];
            float bv[4] = {b4.x, b4.y, b4.z, b4.w};
#pragma unroll
            for (int r = 0; r < 16; ++r)
#pragma unroll
                for (int c = 0; c < 4; ++c)
                    acc[r][c] = fmaf(av[r], bv[c], acc[r][c]);
        }
        __syncthreads();
    }

    float sqi[16], sqj[4];
#pragma unroll
    for (int r = 0; r < 16; ++r) sqi[r] = sq[r0 + ty * 16 + r];
#pragma unroll
    for (int c = 0; c < 4; ++c) sqj[c] = sq[c0 + tx * 4 + c];

    float myd = 0.f;
    int myn = 0;
#pragma unroll
    for (int r = 0; r < 16; ++r) {
#pragma unroll
        for (int c = 0; c < 4; ++c) {
            float v = fmaxf(sqi[r] + sqj[c] - 2.f * acc[r][c], 0.f);
            acc[r][c] = v;
            if (v > 0.f) { myd += sqrtf(v); ++myn; }
        }
        float4 o = {acc[r][0], acc[r][1], acc[r][2], acc[r][3]};
        *(float4*)(d2 + (size_t)(r0 + ty * 16 + r) * NN + c0 + tx * 4) = o;
    }
    if (bi != bj) {
#pragma unroll
        for (int c = 0; c < 4; ++c) {
            size_t base = (size_t)(c0 + tx * 4 + c) * NN + r0 + ty * 16;
            float4 w0 = {acc[0][c],  acc[1][c],  acc[2][c],  acc[3][c]};
            float4 w1 = {acc[4][c],  acc[5][c],  acc[6][c],  acc[7][c]};
            float4 w2 = {acc[8][c],  acc[9][c],  acc[10][c], acc[11][c]};
            float4 w3 = {acc[12][c], acc[13][c], acc[14][c], acc[15][c]};
            *(float4*)(d2 + base + 0)  = w0;
            *(float4*)(d2 + base + 4)  = w1;
            *(float4*)(d2 + base + 8)  = w2;
            *(float4*)(d2 + base + 12) = w3;
        }
    }

    const int w = (bi == bj) ? 1 : 2;
    double dd_ = (double)myd;
#pragma unroll
    for (int off = 32; off > 0; off >>= 1) {
        dd_ += __shfl_down(dd_, off);
        myn += __shfl_down(myn, off);
    }
    int wave = tid >> 6;
    if ((tid & 63) == 0) { red_d[wave] = dd_; red_n[wave] = myn; }
    __syncthreads();
    if (tid == 0) {
        double td = red_d[0] + red_d[1] + red_d[2] + red_d[3];
        int tn = red_n[0] + red_n[1] + red_n[2] + red_n[3];
        atomicAdd(dsum, td * (double)w);
        atomicAdd(nzc, (unsigned long long)(tn * w));
    }
}

__global__ void k_sigmas(const double* __restrict__ dsum, const unsigned long long* __restrict__ nzc,
                         float* __restrict__ csig, double* __restrict__ KL, double* __restrict__ KK) {
    int t = threadIdx.x;
    float mean = (float)(*dsum / (double)(*nzc));
    float lo = 0.1f * mean;
    float hi = 10.0f * mean;
    float step = (hi - lo) / (float)NS;
    if (t < NS) {
        float s = lo + step * (float)t;
        csig[t] = (float)(1.4426950408889634 / ((double)s * (double)s));
        KL[t] = 0.0;
        KK[t] = 0.0;
    }
}

// Sweep v3: 128x128 triangle tile, split into 2 half-tiles (grid.y) of 64 rows.
// 256 threads, 32 elems/thread STREAMED (no persistent register arrays - R5's
// scratch demotion lesson), double-buffered prefetch, packed f32 math.
// NCHUNK sigma-chunks of CH=15 re-read the data from L3 each pass.
template <int CH, int NCHUNK>
__launch_bounds__(256, 4)
__global__ void k_sweep_all(const float* __restrict__ d2, const float* __restrict__ lk,
                            const float* __restrict__ csig, double* __restrict__ KL,
                            double* __restrict__ KK) {
    int bi, bj;
    tri_decode(blockIdx.x, NBSW2, bi, bj);
    const int r0 = bi * SB2 + (int)blockIdx.y * 64;   // 64-row half-tile
    const int c0 = bj * SB2;
    const float w = (bi == bj) ? 1.f : 2.f;

    const int rr = threadIdx.x >> 4;          // 0..15
    const int c8 = (threadIdx.x & 15) * 8;    // 0..120
    const size_t base = (size_t)(r0 + rr) * NN + c0 + c8;

    __shared__ double part[4][2 * CH * NCHUNK];
    const int lane = threadIdx.x & 63, wave = threadIdx.x >> 6;

#pragma unroll 1
    for (int ch = 0; ch < NCHUNK; ++ch) {
        const int s0 = ch * CH;
        float c[CH];
#pragma unroll
        for (int s = 0; s < CH; ++s) c[s] = csig[s0 + s];   // uniform -> scalar loads
        v2f akl[CH], akk[CH];
#pragma unroll
        for (int s = 0; s < CH; ++s) { akl[s] = (v2f){0.f, 0.f}; akk[s] = (v2f){0.f, 0.f}; }

        // prefetch it=0
        float4 pd0 = *(const float4*)(d2 + base);
        float4 pd1 = *(const float4*)(d2 + base + 4);
        float4 pl0 = *(const float4*)(lk + base);
        float4 pl1 = *(const float4*)(lk + base + 4);

#pragma unroll 1
        for (int it = 0; it < 4; ++it) {
            float4 d0 = pd0, d1 = pd1, l0 = pl0, l1 = pl1;
            if (it < 3) {   // issue next-iteration loads; hidden under this iter's compute
                size_t off = base + (size_t)(16 * (it + 1)) * NN;
                pd0 = *(const float4*)(d2 + off);
                pd1 = *(const float4*)(d2 + off + 4);
                pl0 = *(const float4*)(lk + off);
                pl1 = *(const float4*)(lk + off + 4);
            }
            v2f nd[4] = {(v2f){-d0.x, -d0.y}, (v2f){-d0.z, -d0.w},
                         (v2f){-d1.x, -d1.y}, (v2f){-d1.z, -d1.w}};
            v2f L[4]  = {(v2f){l0.x, l0.y}, (v2f){l0.z, l0.w},
                         (v2f){l1.x, l1.y}, (v2f){l1.z, l1.w}};
#pragma unroll
            for (int e = 0; e < 4; ++e) {
#pragma unroll
                for (int s = 0; s < CH; ++s) {
                    v2f arg = nd[e] * c[s];                         // v_pk_mul_f32
                    v2f K = {fexp2(arg.x), fexp2(arg.y)};           // 2x v_exp_f32
                    akl[s] = __builtin_elementwise_fma(K, L[e], akl[s]);   // v_pk_fma_f32
                    akk[s] = __builtin_elementwise_fma(K, K, akk[s]);      // v_pk_fma_f32
                }
            }
        }

#pragma unroll
        for (int s = 0; s < CH; ++s) {
            float v1 = akl[s].x + akl[s].y, v2 = akk[s].x + akk[s].y;
#pragma unroll
            for (int off = 32; off > 0; off >>= 1) {
                v1 += __shfl_down(v1, off);
                v2 += __shfl_down(v2, off);
            }
            if (lane == 0) {
                part[wave][2 * s0 + s]      = (double)(v1 * w);
                part[wave][2 * s0 + CH + s] = (double)(v2 * w);
            }
        }
    }
    __syncthreads();
    const int t = threadIdx.x;
    if (t < 2 * CH * NCHUNK) {
        double v = part[0][t] + part[1][t] + part[2][t] + part[3][t];
        const int ch = t / (2 * CH);          // compile-time divisor
        const int r  = t - ch * 2 * CH;
        if (r < CH) atomicAdd(&KL[ch * CH + r], v);
        else        atomicAdd(&KK[ch * CH + r - CH], v);
    }
}

__global__ void k_argmax(const double* __restrict__ KL, const double* __restrict__ KK,
                         const float* __restrict__ csig, float* __restrict__ copt) {
    if (threadIdx.x == 0 && blockIdx.x == 0) {
        double best = -1.0;
        int bi = 0;
        for (int i = 0; i < NS; ++i) {
            double loss = KL[i] / sqrt(KK[i]);
            if (loss > best) { best = loss; bi = i; }   // strict > keeps FIRST max (jnp.argmax)
        }
        *copt = csig[bi];
    }
}

__launch_bounds__(256)
__global__ void k_final(float* __restrict__ d2, const float* __restrict__ copt) {
    const float c = *copt;
    const float inv_n = 1.0f / (float)NN;
    const int nthreads = gridDim.x * blockDim.x;
    float4* p = (float4*)d2;
    for (int i = blockIdx.x * blockDim.x + threadIdx.x; i < TOT / 4; i += nthreads) {
        float4 v = p[i];
        v.x = fexp2(-v.x * c) * inv_n;
        v.y = fexp2(-v.y * c) * inv_n;
        v.z = fexp2(-v.z * c) * inv_n;
        v.w = fexp2(-v.w * c) * inv_n;
        p[i] = v;
    }
}

extern "C" void kernel_launch(void* const* d_in, const int* in_sizes, int n_in,
                              void* d_out, int out_size, void* d_ws, size_t ws_size,
                              hipStream_t stream) {
    const float* x  = (const float*)d_in[0];
    const float* lk = (const float*)d_in[1];
    float* out = (float*)d_out;   // doubles as the d2 buffer, transformed in place at the end
    char* ws = (char*)d_ws;

    double* dsum = (double*)(ws + 0);
    unsigned long long* nzc = (unsigned long long*)(ws + 8);
    double* KL = (double*)(ws + 16);
    double* KK = (double*)(ws + 16 + 8 * NS);
    float* sqv  = (float*)(ws + 16 + 16 * NS);
    float* csig = (float*)(ws + 16 + 16 * NS + 4 * NN);
    float* copt = (float*)(ws + 16 + 16 * NS + 4 * NN + 4 * NS);

    hipLaunchKernelGGL(k_rowsq, dim3(NN / 256), dim3(256), 0, stream, x, sqv, dsum, nzc);
    hipLaunchKernelGGL(k_d2, dim3(GRID_D2), dim3(256), 0, stream, x, sqv, out, dsum, nzc);
    hipLaunchKernelGGL(k_sigmas, dim3(1), dim3(128), 0, stream, dsum, nzc, csig, KL, KK);
    hipLaunchKernelGGL((k_sweep_all<15, 5>), dim3(GRID_SW2, 2), dim3(256), 0, stream, out, lk, csig, KL, KK);
    hipLaunchKernelGGL(k_argmax, dim3(1), dim3(64), 0, stream, KL, KK, csig, copt);
    hipLaunchKernelGGL(k_final, dim3(2048), dim3(256), 0, stream, out, copt);
}

// Round 7
// 207.774 us; speedup vs baseline: 1.1430x; 1.1430x over previous
//
#include <hip/hip_runtime.h>
#include <hip/hip_bf16.h>

#define NN 4096
#define DD 128
#define NS 75
#define TOT (NN * NN)

// k_d2 tiling
#define BT 128
#define KCC 32
#define NBD2 (NN / BT)                      // 32
#define GRID_D2 (NBD2 * (NBD2 + 1) / 2)     // 528

// sweep tiling: 64x64 tiles, 256 threads, 16 elems/thread (register-resident)
#define SB 64
#define NBSW (NN / SB)                      // 64
#define GRID_SW (NBSW * (NBSW + 1) / 2)     // 2080

typedef float v2f __attribute__((ext_vector_type(2)));

__device__ __forceinline__ float fexp2(float v) { return __builtin_amdgcn_exp2f(v); }

// linear index -> (bi, bj) with bi <= bj, row-major over upper triangle
__device__ __forceinline__ void tri_decode(int t, int nb, int& bi, int& bj) {
    int b = 0, rem = t;
    while (rem >= nb - b) { rem -= nb - b; ++b; }   // uniform across block -> scalar
    bi = b; bj = b + rem;
}

// ---------------- ws layout (bytes) ----------------
// 0                       : double dist_sum
// 8                       : unsigned long long nz_count
// 16                      : double KL[NS]
// 16 + 8*NS               : double KK[NS]
// 16 + 16*NS              : float sq[NN]
// 16 + 16*NS + 4*NN       : float csig[NS]   (log2e / sigma_s^2)
// 16 + 16*NS + 4*NN + 4*NS: float copt

__global__ void k_rowsq(const float* __restrict__ x, float* __restrict__ sq,
                        double* __restrict__ dsum, unsigned long long* __restrict__ nzc) {
    int tid = blockIdx.x * blockDim.x + threadIdx.x;
    if (tid == 0) { *dsum = 0.0; *nzc = 0ull; }
    if (tid < NN) {
        const float4* row = (const float4*)(x + (size_t)tid * DD);
        float s = 0.f;
#pragma unroll
        for (int i = 0; i < DD / 4; ++i) {
            float4 v = row[i];
            s += v.x * v.x + v.y * v.y + v.z * v.z + v.w * v.w;
        }
        sq[tid] = s;
    }
}

// 128x128 output tile per block, upper-triangle grid, mirrored writes.
__launch_bounds__(256)
__global__ void k_d2(const float* __restrict__ x, const float* __restrict__ sq,
                     float* __restrict__ d2, double* __restrict__ dsum,
                     unsigned long long* __restrict__ nzc) {
    __shared__ float at[KCC][BT + 4];   // stride 132: 16B-aligned b128 reads, writes 4-way max
    __shared__ float btl[KCC][BT + 4];
    __shared__ double red_d[4];
    __shared__ int red_n[4];

    int bi, bj;
    tri_decode(blockIdx.x, NBD2, bi, bj);
    const int r0 = bi * BT, c0 = bj * BT;
    const int tid = threadIdx.x;
    const int tx = tid & 31;   // col group: 4 cols
    const int ty = tid >> 5;   // row group: 16 rows

    float acc[16][4];
#pragma unroll
    for (int r = 0; r < 16; ++r)
#pragma unroll
        for (int c = 0; c < 4; ++c) acc[r][c] = 0.f;

    for (int kb = 0; kb < DD; kb += KCC) {
#pragma unroll
        for (int i = 0; i < 4; ++i) {
            int idx = tid + 256 * i;       // 0..1023
            int row = idx >> 3;            // 0..127
            int k4 = (idx & 7) * 4;        // 0..28
            float4 va = *(const float4*)(x + (size_t)(r0 + row) * DD + kb + k4);
            at[k4 + 0][row] = va.x; at[k4 + 1][row] = va.y;
            at[k4 + 2][row] = va.z; at[k4 + 3][row] = va.w;
            float4 vb = *(const float4*)(x + (size_t)(c0 + row) * DD + kb + k4);
            btl[k4 + 0][row] = vb.x; btl[k4 + 1][row] = vb.y;
            btl[k4 + 2][row] = vb.z; btl[k4 + 3][row] = vb.w;
        }
        __syncthreads();
#pragma unroll
        for (int kk = 0; kk < KCC; ++kk) {
            float av[16];
            *(float4*)&av[0]  = *(const float4*)&at[kk][ty * 16 + 0];
            *(float4*)&av[4]  = *(const float4*)&at[kk][ty * 16 + 4];
            *(float4*)&av[8]  = *(const float4*)&at[kk][ty * 16 + 8];
            *(float4*)&av[12] = *(const float4*)&at[kk][ty * 16 + 12];
            float4 b4 = *(const float4*)&btl[kk][tx * 4];
            float bv[4] = {b4.x, b4.y, b4.z, b4.w};
#pragma unroll
            for (int r = 0; r < 16; ++r)
#pragma unroll
                for (int c = 0; c < 4; ++c)
                    acc[r][c] = fmaf(av[r], bv[c], acc[r][c]);
        }
        __syncthreads();
    }

    float sqi[16], sqj[4];
#pragma unroll
    for (int r = 0; r < 16; ++r) sqi[r] = sq[r0 + ty * 16 + r];
#pragma unroll
    for (int c = 0; c < 4; ++c) sqj[c] = sq[c0 + tx * 4 + c];

    float myd = 0.f;
    int myn = 0;
#pragma unroll
    for (int r = 0; r < 16; ++r) {
#pragma unroll
        for (int c = 0; c < 4; ++c) {
            float v = fmaxf(sqi[r] + sqj[c] - 2.f * acc[r][c], 0.f);
            acc[r][c] = v;
            if (v > 0.f) { myd += sqrtf(v); ++myn; }
        }
        float4 o = {acc[r][0], acc[r][1], acc[r][2], acc[r][3]};
        *(float4*)(d2 + (size_t)(r0 + ty * 16 + r) * NN + c0 + tx * 4) = o;
    }
    if (bi != bj) {
#pragma unroll
        for (int c = 0; c < 4; ++c) {
            size_t base = (size_t)(c0 + tx * 4 + c) * NN + r0 + ty * 16;
            float4 w0 = {acc[0][c],  acc[1][c],  acc[2][c],  acc[3][c]};
            float4 w1 = {acc[4][c],  acc[5][c],  acc[6][c],  acc[7][c]};
            float4 w2 = {acc[8][c],  acc[9][c],  acc[10][c], acc[11][c]};
            float4 w3 = {acc[12][c], acc[13][c], acc[14][c], acc[15][c]};
            *(float4*)(d2 + base + 0)  = w0;
            *(float4*)(d2 + base + 4)  = w1;
            *(float4*)(d2 + base + 8)  = w2;
            *(float4*)(d2 + base + 12) = w3;
        }
    }

    const int w = (bi == bj) ? 1 : 2;
    double dd_ = (double)myd;
#pragma unroll
    for (int off = 32; off > 0; off >>= 1) {
        dd_ += __shfl_down(dd_, off);
        myn += __shfl_down(myn, off);
    }
    int wave = tid >> 6;
    if ((tid & 63) == 0) { red_d[wave] = dd_; red_n[wave] = myn; }
    __syncthreads();
    if (tid == 0) {
        double td = red_d[0] + red_d[1] + red_d[2] + red_d[3];
        int tn = red_n[0] + red_n[1] + red_n[2] + red_n[3];
        atomicAdd(dsum, td * (double)w);
        atomicAdd(nzc, (unsigned long long)(tn * w));
    }
}

__global__ void k_sigmas(const double* __restrict__ dsum, const unsigned long long* __restrict__ nzc,
                         float* __restrict__ csig, double* __restrict__ KL, double* __restrict__ KK) {
    int t = threadIdx.x;
    float mean = (float)(*dsum / (double)(*nzc));
    float lo = 0.1f * mean;
    float hi = 10.0f * mean;
    float step = (hi - lo) / (float)NS;
    if (t < NS) {
        float s = lo + step * (float)t;
        csig[t] = (float)(1.4426950408889634 / ((double)s * (double)s));
        KL[t] = 0.0;
        KK[t] = 0.0;
    }
}

// Sweep v4 = R4 structure + packed f32 math + wider VGPR cap.
// 64x64 tile/block (upper-tri grid, off-diag weight 2), 16 elems/thread
// loaded ONCE into v2f regs (32 VGPR); NCHUNK chunks of CH sigmas iterate
// over register-resident data with v_pk_mul/v_pk_fma + v_exp_f32.
// launch_bounds(256,3): VGPR cap ~170 so data+acc (~110) stay arch-VGPR.
template <int CH, int NCHUNK>
__launch_bounds__(256, 3)
__global__ void k_sweep_all(const float* __restrict__ d2, const float* __restrict__ lk,
                            const float* __restrict__ csig, double* __restrict__ KL,
                            double* __restrict__ KK) {
    int bi, bj;
    tri_decode(blockIdx.x, NBSW, bi, bj);
    const int r0 = bi * SB, c0 = bj * SB;
    const float w = (bi == bj) ? 1.f : 2.f;

    const int rr = threadIdx.x >> 4;          // 0..15
    const int c4 = (threadIdx.x & 15) * 4;    // 0..60

    v2f nd[8], ll[8];                          // 32 VGPR, live across all chunks
#pragma unroll
    for (int it = 0; it < 4; ++it) {
        size_t off = (size_t)(r0 + rr + 16 * it) * NN + c0 + c4;
        float4 dv = *(const float4*)(d2 + off);
        float4 lv = *(const float4*)(lk + off);
        nd[it * 2 + 0] = (v2f){-dv.x, -dv.y};
        nd[it * 2 + 1] = (v2f){-dv.z, -dv.w};
        ll[it * 2 + 0] = (v2f){lv.x, lv.y};
        ll[it * 2 + 1] = (v2f){lv.z, lv.w};
    }

    __shared__ double part[4][2 * CH * NCHUNK];
    const int lane = threadIdx.x & 63, wave = threadIdx.x >> 6;

#pragma unroll 1
    for (int ch = 0; ch < NCHUNK; ++ch) {
        const int s0 = ch * CH;
        float c[CH];
#pragma unroll
        for (int s = 0; s < CH; ++s) c[s] = csig[s0 + s];   // uniform -> SGPR
        v2f akl[CH], akk[CH];
#pragma unroll
        for (int s = 0; s < CH; ++s) { akl[s] = (v2f){0.f, 0.f}; akk[s] = (v2f){0.f, 0.f}; }

#pragma unroll
        for (int e = 0; e < 8; ++e) {
            v2f ndv = nd[e], L = ll[e];
#pragma unroll
            for (int s = 0; s < CH; ++s) {
                v2f arg = ndv * c[s];                               // v_pk_mul_f32
                v2f K = {fexp2(arg.x), fexp2(arg.y)};               // 2x v_exp_f32
                akl[s] = __builtin_elementwise_fma(K, L, akl[s]);   // v_pk_fma_f32
                akk[s] = __builtin_elementwise_fma(K, K, akk[s]);   // v_pk_fma_f32
            }
        }

#pragma unroll
        for (int s = 0; s < CH; ++s) {
            float v1 = akl[s].x + akl[s].y, v2 = akk[s].x + akk[s].y;
#pragma unroll
            for (int off = 32; off > 0; off >>= 1) {
                v1 += __shfl_down(v1, off);
                v2 += __shfl_down(v2, off);
            }
            if (lane == 0) {
                part[wave][2 * s0 + s]      = (double)(v1 * w);
                part[wave][2 * s0 + CH + s] = (double)(v2 * w);
            }
        }
    }
    __syncthreads();
    const int t = threadIdx.x;
    if (t < 2 * CH * NCHUNK) {
        double v = part[0][t] + part[1][t] + part[2][t] + part[3][t];
        const int ch = t / (2 * CH);          // compile-time divisor
        const int r  = t - ch * 2 * CH;
        if (r < CH) atomicAdd(&KL[ch * CH + r], v);
        else        atomicAdd(&KK[ch * CH + r - CH], v);
    }
}

__global__ void k_argmax(const double* __restrict__ KL, const double* __restrict__ KK,
                         const float* __restrict__ csig, float* __restrict__ copt) {
    if (threadIdx.x == 0 && blockIdx.x == 0) {
        double best = -1.0;
        int bi = 0;
        for (int i = 0; i < NS; ++i) {
            double loss = KL[i] / sqrt(KK[i]);
            if (loss > best) { best = loss; bi = i; }   // strict > keeps FIRST max (jnp.argmax)
        }
        *copt = csig[bi];
    }
}

__launch_bounds__(256)
__global__ void k_final(float* __restrict__ d2, const float* __restrict__ copt) {
    const float c = *copt;
    const float inv_n = 1.0f / (float)NN;
    const int nthreads = gridDim.x * blockDim.x;
    float4* p = (float4*)d2;
    for (int i = blockIdx.x * blockDim.x + threadIdx.x; i < TOT / 4; i += nthreads) {
        float4 v = p[i];
        v.x = fexp2(-v.x * c) * inv_n;
        v.y = fexp2(-v.y * c) * inv_n;
        v.z = fexp2(-v.z * c) * inv_n;
        v.w = fexp2(-v.w * c) * inv_n;
        p[i] = v;
    }
}

extern "C" void kernel_launch(void* const* d_in, const int* in_sizes, int n_in,
                              void* d_out, int out_size, void* d_ws, size_t ws_size,
                              hipStream_t stream) {
    const float* x  = (const float*)d_in[0];
    const float* lk = (const float*)d_in[1];
    float* out = (float*)d_out;   // doubles as the d2 buffer, transformed in place at the end
    char* ws = (char*)d_ws;

    double* dsum = (double*)(ws + 0);
    unsigned long long* nzc = (unsigned long long*)(ws + 8);
    double* KL = (double*)(ws + 16);
    double* KK = (double*)(ws + 16 + 8 * NS);
    float* sqv  = (float*)(ws + 16 + 16 * NS);
    float* csig = (float*)(ws + 16 + 16 * NS + 4 * NN);
    float* copt = (float*)(ws + 16 + 16 * NS + 4 * NN + 4 * NS);

    hipLaunchKernelGGL(k_rowsq, dim3(NN / 256), dim3(256), 0, stream, x, sqv, dsum, nzc);
    hipLaunchKernelGGL(k_d2, dim3(GRID_D2), dim3(256), 0, stream, x, sqv, out, dsum, nzc);
    hipLaunchKernelGGL(k_sigmas, dim3(1), dim3(128), 0, stream, dsum, nzc, csig, KL, KK);
    hipLaunchKernelGGL((k_sweep_all<15, 5>), dim3(GRID_SW), dim3(256), 0, stream, out, lk, csig, KL, KK);
    hipLaunchKernelGGL(k_argmax, dim3(1), dim3(64), 0, stream, KL, KK, csig, copt);
    hipLaunchKernelGGL(k_final, dim3(2048), dim3(256), 0, stream, out, copt);
}